// Round 5
// baseline (19.206 us; speedup 1.0000x reference)
//
#include <hip/hip_runtime.h>
#include <hip/hip_bf16.h>
#include <math.h>

// PillarFeatureNet fully inside MFMA k-space (see R4 comments for k-slot map).
// R5 change: NITER 8 -> 4 (halve live VGPR state; avoid the 128-reg cap of
// __launch_bounds__(.,4)), grid 1250 -> 2500 blocks for cross-wave latency
// hiding. Body unchanged.

#define NPIL  40000
#define NITER 4
#define WPB   4
#define BLOCK (WPB * 64)
#define NBLK  (NPIL / (WPB * NITER))   // 2500

typedef float f32x16 __attribute__((ext_vector_type(16)));
typedef short bf16x8 __attribute__((ext_vector_type(8)));

union frag_u { bf16x8 h; int4 w; };

__device__ __forceinline__ int pk(float a, float b) {
    unsigned lo = (unsigned)__bfloat16_as_ushort(__float2bfloat16(a));
    unsigned hi = (unsigned)__bfloat16_as_ushort(__float2bfloat16(b));
    return (int)(lo | (hi << 16));
}
__device__ __forceinline__ float bfround(float x) {
    return __bfloat162float(__float2bfloat16(x));
}

template<int CTRL>
__device__ __forceinline__ float dpp_add(float x) {
    return x + __int_as_float(__builtin_amdgcn_update_dpp(
        0, __float_as_int(x), CTRL, 0xF, 0xF, true));
}
__device__ __forceinline__ float lo32_sum(float x) {
    x = dpp_add<0x111>(x);   // row_shr:1
    x = dpp_add<0x112>(x);   // row_shr:2
    x = dpp_add<0x114>(x);   // row_shr:4
    x = dpp_add<0x118>(x);   // row_shr:8
    x = dpp_add<0x142>(x);   // row_bcast:15 -> lane31 = sum(0..31)
    return __int_as_float(__builtin_amdgcn_readlane(__float_as_int(x), 31));
}

__device__ __forceinline__ float vmax16(const f32x16& a) {
    float t0 = fmaxf(fmaxf(a[0],  a[1]),  a[2]);
    float t1 = fmaxf(fmaxf(a[3],  a[4]),  a[5]);
    float t2 = fmaxf(fmaxf(a[6],  a[7]),  a[8]);
    float t3 = fmaxf(fmaxf(a[9],  a[10]), a[11]);
    float t4 = fmaxf(fmaxf(a[12], a[13]), a[14]);
    float u0 = fmaxf(fmaxf(t0, t1), t2);
    float u1 = fmaxf(fmaxf(t3, t4), a[15]);
    return fmaxf(u0, u1);
}

__global__ __launch_bounds__(BLOCK)
void pfn_mfma_kernel(const float* __restrict__ features,   // [N,32,4]
                     const int*   __restrict__ num_voxels, // [N]
                     const int*   __restrict__ coors,      // [N,4]
                     const float* __restrict__ Wm,         // [64,9]
                     const float* __restrict__ gamma,
                     const float* __restrict__ beta,
                     const float* __restrict__ rmean,
                     const float* __restrict__ rvar,
                     float* __restrict__ out)               // [N,64]
{
    const int  lane = threadIdx.x & 63;
    const int  wid  = threadIdx.x >> 6;
    const int  lo31 = lane & 31;
    const bool hih  = (lane >= 32);

    const int p0 = (blockIdx.x * WPB + wid) * NITER;   // contiguous pillars

    // ---- issue ALL memory up front: NITER feature tiles + batched nv/coors ----
    const float* fbase = features + (size_t)p0 * 128 + lo31 * 4;
    float4 qv[NITER];
    #pragma unroll
    for (int j = 0; j < NITER; ++j)
        qv[j] = *reinterpret_cast<const float4*>(fbase + (size_t)j * 128);
    const int  li   = (lane < NITER) ? lane : (NITER - 1);
    const int  nv8  = num_voxels[p0 + li];
    const int2 cc8  = *reinterpret_cast<const int2*>(coors + (p0 + li) * 4 + 2);

    // ---- per-lane B-fragments (col = lane&31 = unit; built once) ----
    frag_u bf0, bf1;
    {
        const int u = lo31;
        #pragma unroll
        for (int t = 0; t < 2; ++t) {
            const int uu = u + t * 32;
            const float* w = Wm + uu * 9;
            const float s  = gamma[uu] * rsqrtf(rvar[uu] + 1e-3f);
            const float tb = beta[uu] - rmean[uu] * s;
            int4 r;
            if (!hih) {                       // k0-7 chunk
                r.x = pk((w[0] + w[4] + w[7]) * s, (w[1] + w[5] + w[8]) * s);
                r.y = pk((w[2] + w[6]) * s,        w[3] * s);
                r.z = pk(w[4] * s,                 w[5] * s);
                r.w = pk(w[6] * s,                 0.0f);
            } else {                          // k8-15 chunk
                const float w7s = w[7] * s, w8s = w[8] * s;
                r.x = pk(w7s, w7s);
                r.y = pk(w8s, w8s);
                r.z = pk(tb,  tb - bfround(tb));   // (tb_hi, tb_lo)
                r.w = 0;
            }
            if (t == 0) bf0.w = r; else bf1.w = r;
        }
    }

    f32x16 z;
    #pragma unroll
    for (int i = 0; i < 16; ++i) z[i] = 0.0f;

    const int ONE2 = 0x3F803F80;                 // pack(1.0bf, 1.0bf)
    const int inv2 = hih ? ONE2 : 0;

    #pragma unroll
    for (int j = 0; j < NITER; ++j) {
        const int   snv = __builtin_amdgcn_readlane(nv8,   j);
        const int   sc2 = __builtin_amdgcn_readlane(cc8.x, j);
        const int   sc3 = __builtin_amdgcn_readlane(cc8.y, j);
        const float4 q  = qv[j];

        // pillar mean over all 32 rows (reference: full sum / nv)
        const float S0 = lo32_sum(q.x);
        const float S1 = lo32_sum(q.y);
        const float S2 = lo32_sum(q.z);
        const float rn = __builtin_amdgcn_rcpf((float)snv);
        const float cx = (float)sc3 * 0.2f + 0.1f;
        const float cy = (float)sc2 * 0.2f + (0.1f - 40.0f);

        const int f01 = pk(q.x, q.y);
        const int f23 = pk(q.z, q.w);
        const int mxy = pk(-S0 * rn, -S1 * rn);
        const int mz0 = pk(-S2 * rn, 0.0f);
        const int cxw = pk(-cx, -cx - bfround(-cx));
        const int cyw = pk(-cy, -cy - bfround(-cy));

        const bool valid = (lo31 < snv);
        int w0 = hih ? cxw  : f01;  w0 = valid ? w0 : 0;
        int w1 = hih ? cyw  : f23;  w1 = valid ? w1 : 0;
        int w2 = hih ? ONE2 : mxy;  w2 = valid ? w2 : inv2;   // k12/13 never masked
        int w3 = hih ? 0    : mz0;  w3 = valid ? w3 : 0;
        frag_u af; af.w = make_int4(w0, w1, w2, w3);

        const f32x16 a0 = __builtin_amdgcn_mfma_f32_32x32x16_bf16(af.h, bf0.h, z, 0, 0, 0);
        const f32x16 a1 = __builtin_amdgcn_mfma_f32_32x32x16_bf16(af.h, bf1.h, z, 0, 0, 0);

        const float m0 = vmax16(a0);
        const float m1 = vmax16(a1);
        const float got  = __shfl_xor(hih ? m0 : m1, 32, 64);
        const float mine = hih ? m1 : m0;
        const float r = fmaxf(fmaxf(mine, got), 0.0f);

        out[(size_t)(p0 + j) * 64 + lane] = r;
    }
}

extern "C" void kernel_launch(void* const* d_in, const int* in_sizes, int n_in,
                              void* d_out, int out_size, void* d_ws, size_t ws_size,
                              hipStream_t stream) {
    const float* features   = (const float*)d_in[0];
    const int*   num_voxels = (const int*)  d_in[1];
    const int*   coors      = (const int*)  d_in[2];
    const float* Wm         = (const float*)d_in[3];
    const float* gamma      = (const float*)d_in[4];
    const float* beta       = (const float*)d_in[5];
    const float* rmean      = (const float*)d_in[6];
    const float* rvar       = (const float*)d_in[7];
    float*       out        = (float*)d_out;

    hipLaunchKernelGGL(pfn_mfma_kernel, dim3(NBLK), dim3(BLOCK), 0, stream,
                       features, num_voxels, coors, Wm, gamma, beta, rmean, rvar, out);
}